// Round 8
// baseline (179.248 us; speedup 1.0000x reference)
//
#include <hip/hip_runtime.h>
#include <hip/hip_bf16.h>
#include <stdint.h>

#define BB 2
#define CC 256
#define HH 96
#define WW 320
#define NPIX 16384
#define NLAY 5
#define KDIM 1280   // CC*NLAY
#define NDIM 32768  // BB*NPIX
#define NGRP 256    // NDIM/128 mask groups
#define BSP 264     // Bs row pitch in bf16 (256 + 8 pad)

typedef float f32x4 __attribute__((ext_vector_type(4)));
typedef float f32x2 __attribute__((ext_vector_type(2)));
typedef __bf16 bf16x8 __attribute__((ext_vector_type(8)));
typedef __bf16 bf16x4 __attribute__((ext_vector_type(4)));

// ---------- K1 (+K3+K5 fused as extra blocks): ----------
// blocks [0,480): box geometry + Wc repack (overlap with k1, R4) + mask (R5).
// blocks [480, 480+1536): cumsum along W + transpose (B,C,H,W)->(B,H,W,C).
//   R8: reverted to R3's 1-barrier form — direct global run-reads (lane owns
//   w in [5*lane,5*lane+5), 2 channel streams), scan, transpose tile, float4
//   full-line stores. R4's LDS read-staging (3 barriers) measured neutral;
//   removing it cuts 2 barriers + an LDS round trip.
__global__ __launch_bounds__(1024) void k1f(const float* __restrict__ feat,
                                            float* __restrict__ integ,
                                            const float* __restrict__ gridp,
                                            const float* __restrict__ calib,
                                            const float* __restrict__ Wc,
                                            float4* __restrict__ coords,
                                            float* __restrict__ scales,
                                            __bf16* __restrict__ Wbf,
                                            uint8_t* __restrict__ mask8) {
  const int bid = blockIdx.x;
  if (bid < 480) {
    // ---- K3/K5 part ----
    const int vbid = bid * 4 + (threadIdx.x >> 8);
    const int vt = threadIdx.x & 255;
    if (vbid >= 640) {                  // K5: repack Wc (co, c*5+n) -> bf16 (co, n*256+c)
      int o = (vbid - 640) * 256 + vt;
      int co = o / KDIM;
      int kk = o % KDIM;
      int n = kk >> 8;
      int c = kk & 255;
      Wbf[o] = (__bf16)Wc[co * KDIM + c * NLAY + n];
      return;
    }
    // K3: one thread per box.
    int box = vbid * 256 + vt;          // ((b*5+n)<<14) | pix
    int pix = box & (NPIX - 1);
    int bn = box >> 14;
    int n = bn % NLAY;
    int b = bn / NLAY;
    const float* cb = calib + b * 12;
    float c00 = cb[0], c01 = cb[1], c02 = cb[2], c03 = cb[3];
    float c10 = cb[4], c11 = cb[5], c12 = cb[6], c13 = cb[7];
    float c20 = cb[8], c21 = cb[9], c22 = cb[10], c23 = cb[11];
    float gx = gridp[pix * 3 + 0], gy = gridp[pix * 3 + 1], gz = gridp[pix * 3 + 2];
    float zoff = 32.0f * (float)n;
    const float ox[8] = {-12.5f, 12.5f, 12.5f, -12.5f, -12.5f, 12.5f, 12.5f, -12.5f};
    const float oy[8] = {-12.5f, -12.5f, 12.5f, 12.5f, -12.5f, -12.5f, 12.5f, 12.5f};
    float xmn = 1e30f, ymn = 1e30f, xmx = -1e30f, ymx = -1e30f;
#pragma unroll
    for (int k = 0; k < 8; ++k) {
      float X = gx + ox[k];
      float Y = gy + oy[k];
      float Z = gz + zoff + ((k >= 4) ? 32.0f : 0.0f);
      float px = c00 * X + c01 * Y + c02 * Z + c03;
      float py = c10 * X + c11 * Y + c12 * Z + c13;
      float pz = c20 * X + c21 * Y + c22 * Z + c23;
      float d = fmaxf(pz, 1e-6f);
      float nx = fminf(fmaxf(2.0f * (px / d) / 320.0f - 1.0f, -1.0f), 0.95f);
      float ny = fminf(fmaxf(2.0f * (py / d) / 96.0f - 1.0f, -1.0f), 0.95f);
      xmn = fminf(xmn, nx); xmx = fmaxf(xmx, nx);
      ymn = fminf(ymn, ny); ymx = fmaxf(ymx, ny);
    }
    float dx = xmx - xmn, dy = ymx - ymn;
    float area = (dx * dy) * 30720.0f + 1e-6f;
    bool vis = (area > 1e-6f) && (area < 9216.0f);
    {
      __shared__ uint32_t kf[16];
      unsigned long long bal = __ballot(vis);
      if ((threadIdx.x & 63) == 0) kf[threadIdx.x >> 6] = (bal != 0ull) ? 1u : 0u;
      __syncthreads();
      if (vt == 0) {
        int vb = threadIdx.x >> 8;      // vbid-local 0..3
        int vbid2 = bid * 4 + vb;
        int bn2 = vbid2 >> 6;
        int n2 = bn2 % NLAY, b2 = bn2 / NLAY;
        int g0 = b2 * 128 + (vbid2 & 63) * 2;
        mask8[g0 * 5 + n2]       = (uint8_t)(kf[vb * 4 + 0] | kf[vb * 4 + 1]);
        mask8[(g0 + 1) * 5 + n2] = (uint8_t)(kf[vb * 4 + 2] | kf[vb * 4 + 3]);
      }
    }
    float X0 = ((xmn + 1.0f) * 320.0f - 1.0f) * 0.5f;
    float Y0 = ((ymn + 1.0f) * 96.0f - 1.0f) * 0.5f;
    float X1 = ((xmx + 1.0f) * 320.0f - 1.0f) * 0.5f;
    float Y1 = ((ymx + 1.0f) * 96.0f - 1.0f) * 0.5f;
    coords[box] = make_float4(X0, Y0, X1, Y1);
    scales[box] = vis ? 1.0f / area : 0.0f;
    return;
  }
  // ---- K1 part: 32 channels per block, wave scans 2 channel rows ----
  __shared__ float tile[WW * 33];       // pitch 33: run-write stride 165%32=5
                                        // (2-way, free); f4-read (w+4cq) 2-way
  const int t = threadIdx.x;
  const int wave = t >> 6;
  const int lane = t & 63;
  const int kb = bid - 480;
  const int cg = kb & 7;
  const int h = (kb >> 3) % HH;
  const int b = kb / (8 * HH);
  const int c0 = cg * 32 + wave * 2;
  const float* s0 = feat + (size_t)((b * CC + c0) * HH + h) * WW;
  const float* s1 = s0 + (size_t)HH * WW;

  float va[5], vb[5];
#pragma unroll
  for (int j = 0; j < 5; ++j) va[j] = s0[lane * 5 + j];
#pragma unroll
  for (int j = 0; j < 5; ++j) vb[j] = s1[lane * 5 + j];
#pragma unroll
  for (int j = 1; j < 5; ++j) { va[j] += va[j - 1]; vb[j] += vb[j - 1]; }
  float ta = va[4], tb = vb[4];
  float ia = ta, ib = tb;
#pragma unroll
  for (int d = 1; d < 64; d <<= 1) {
    float ua = __shfl_up(ia, d, 64);
    float ub = __shfl_up(ib, d, 64);
    if (lane >= d) { ia += ua; ib += ub; }
  }
  float pa = ia - ta, pb = ib - tb;     // exclusive prefixes
#pragma unroll
  for (int j = 0; j < 5; ++j) { va[j] += pa; vb[j] += pb; }
  const int ca = wave * 2, cbn = wave * 2 + 1;
#pragma unroll
  for (int j = 0; j < 5; ++j) {
    int w = lane * 5 + j;
    tile[w * 33 + ca]  = va[j];
    tile[w * 33 + cbn] = vb[j];
  }
  __syncthreads();
  // store: float4 per thread; per wave-instr 8 w-rows x 128B full-line segs
  float* dst = integ + (size_t)((b * HH + h) * WW) * CC + (cg * 32);
#pragma unroll
  for (int r = 0; r < 3; ++r) {
    int idx = r * 1024 + t;             // 0..2559
    if (idx < 2560) {
      int w = idx >> 3;
      int cq = (idx & 7) * 4;
      float4 o = make_float4(tile[w * 33 + cq + 0], tile[w * 33 + cq + 1],
                             tile[w * 33 + cq + 2], tile[w * 33 + cq + 3]);
      *(float4*)(dst + (size_t)w * CC + cq) = o;
    }
  }
}

// ---------- K2: cumsum along H, in place on (B,H,W,C) ----------
// Two-level scan, f32x4 per lane (1KB segments/wave-instr, 24-deep ILP).
__global__ __launch_bounds__(256) void k2_scan(float* __restrict__ integ) {
  const int blk = blockIdx.x;            // (b, w)
  const int w = blk % WW;
  const int b = blk / WW;
  const int g = threadIdx.x >> 6;        // 0..3 h-group
  const int l = threadIdx.x & 63;
  float* base = integ + ((size_t)(b * HH + g * 24) * WW + w) * CC + l * 4;
  const size_t stride = (size_t)WW * CC;
  f32x4 v[24];
#pragma unroll
  for (int i = 0; i < 24; ++i) v[i] = *(const f32x4*)(base + (size_t)i * stride);
#pragma unroll
  for (int i = 1; i < 24; ++i) v[i] += v[i - 1];
  __shared__ f32x4 part[4][64];
  part[g][l] = v[23];
  __syncthreads();
  f32x4 off = {0.f, 0.f, 0.f, 0.f};
#pragma unroll
  for (int gg = 0; gg < 3; ++gg)
    if (gg < g) off += part[gg][l];
#pragma unroll
  for (int i = 0; i < 24; ++i) *(f32x4*)(base + (size_t)i * stride) = v[i] + off;
}

// ---------- K46 v3: fused vox-gather + GEMM ----------
// R7 structure (32-pix blocks, 4/CU, direct-global A, barrier-free MFMA)
// kept. R8: gather made BRANCH-FREE inside visible boxes — all 16 taps use
// clamped indices + zero weights for OOB (0*finite = 0, identical math), so
// the compiler can hoist 16 independent loads per box (x4 boxes per wave)
// against the ~200-900cy L2/L3 latency. R7's per-jj branch gating allowed
// only ~4 in flight -> 40.8us latency-bound (hbm 10%, FETCH ~0).
// __launch_bounds__(512,8) pins VGPR<=64 so 4 blocks/CU (32 waves) holds.
__global__ __launch_bounds__(512, 8) void k46(const __bf16* __restrict__ A,   // Wbf 256 x 1280
                                              const float* __restrict__ integ,
                                              const float4* __restrict__ coords,
                                              const float* __restrict__ scales,
                                              const float* __restrict__ bias,
                                              float* __restrict__ out,
                                              const uint8_t* __restrict__ mask8) {
  __shared__ __align__(16) __bf16 Bs[32 * BSP];      // 16.9 KB
  const int g = blockIdx.x;            // (b, 32-pix tile)
  const int b = g >> 9;
  const int pix0 = (g & 511) * 32;
  const int gm = b * 128 + (pix0 >> 7);   // 128-pix mask group
  const int tid = threadIdx.x;
  const int lane = tid & 63;
  const int wave = tid >> 6;
  const int wm = (wave >> 1) * 64;     // M quadrant (co)
  const int wn = (wave & 1) * 16;      // N half (pix)
  const int r16 = lane & 15;
  const int q4 = lane >> 4;

  // active-layer list (block-uniform)
  int ln[NLAY], nact = 0;
#pragma unroll
  for (int n = 0; n < NLAY; ++n)
    if (mask8[gm * 5 + n]) ln[nact++] = n;

  f32x4 acc[4];
#pragma unroll
  for (int i = 0; i < 4; ++i) acc[i] = f32x4{0.f, 0.f, 0.f, 0.f};

  for (int la = 0; la < nact; ++la) {
    const int n = ln[la];
    const int bn = b * NLAY + n;
    // ---- PHASE G: 4 boxes per wave -> Bs[32][BSP], branch-free taps ----
    const float* gbase = integ + (size_t)(b * HH) * WW * CC + lane * 4;
#pragma unroll
    for (int u = 0; u < 4; ++u) {
      const int row = wave * 4 + u;
      const int box = (bn << 14) | (pix0 + row);
      bf16x4* dst = (bf16x4*)(&Bs[row * BSP + lane * 4]);
      const float scale = scales[box];
      if (scale == 0.f) {               // wave-uniform
        *dst = bf16x4{(__bf16)0.f, (__bf16)0.f, (__bf16)0.f, (__bf16)0.f};
        continue;
      }
      const float4 q = coords[box];
      float xw[4]; int xi[4];
      float yw[4]; int yi[4];
      {
        float f0 = floorf(q.x); int i0 = (int)f0; float w1 = q.x - f0;
        xw[0] = (i0 >= 0 && i0 < WW) ? (1.f - w1) : 0.f;
        xw[1] = (i0 + 1 < WW) ? w1 : 0.f;
        xi[0] = min(max(i0, 0), WW - 1); xi[1] = min(max(i0 + 1, 0), WW - 1);
        float f1 = floorf(q.z); int i1 = (int)f1; float v1 = q.z - f1;
        xw[2] = (i1 >= 0 && i1 < WW) ? -(1.f - v1) : 0.f;
        xw[3] = (i1 + 1 < WW) ? -v1 : 0.f;
        xi[2] = min(max(i1, 0), WW - 1); xi[3] = min(max(i1 + 1, 0), WW - 1);
      }
      {
        float f0 = floorf(q.y); int j0 = (int)f0; float w1 = q.y - f0;
        yw[0] = (j0 >= 0 && j0 < HH) ? (1.f - w1) : 0.f;
        yw[1] = (j0 + 1 < HH) ? w1 : 0.f;
        yi[0] = min(max(j0, 0), HH - 1); yi[1] = min(max(j0 + 1, 0), HH - 1);
        float f1 = floorf(q.w); int j1 = (int)f1; float v1 = q.w - f1;
        yw[2] = (j1 >= 0 && j1 < HH) ? -(1.f - v1) : 0.f;
        yw[3] = (j1 + 1 < HH) ? -v1 : 0.f;
        yi[2] = min(max(j1, 0), HH - 1); yi[3] = min(max(j1 + 1, 0), HH - 1);
      }
      f32x4 val = {0.f, 0.f, 0.f, 0.f};
#pragma unroll
      for (int jj = 0; jj < 4; ++jj) {        // NO branches: 16 independent loads
        const float* rp = gbase + (size_t)yi[jj] * WW * CC;
        f32x4 rs = xw[0] * *(const f32x4*)(rp + (size_t)xi[0] * CC)
                 + xw[1] * *(const f32x4*)(rp + (size_t)xi[1] * CC)
                 + xw[2] * *(const f32x4*)(rp + (size_t)xi[2] * CC)
                 + xw[3] * *(const f32x4*)(rp + (size_t)xi[3] * CC);
        val += yw[jj] * rs;
      }
      val *= scale;
      *dst = bf16x4{(__bf16)val.x, (__bf16)val.y, (__bf16)val.z, (__bf16)val.w};
    }
    __syncthreads();                    // Bs ready
    // ---- PHASE M: 8 K-tiles, direct-global A frags, no barriers ----
    const int kbase = n * 256;
#pragma unroll
    for (int kk = 0; kk < 8; ++kk) {
      const int k0 = kbase + kk * 32;
      bf16x8 af[4];
#pragma unroll
      for (int i = 0; i < 4; ++i)
        af[i] = *(const bf16x8*)(A + (size_t)(wm + i * 16 + r16) * KDIM + k0 + q4 * 8);
      bf16x8 bg = *(const bf16x8*)(&Bs[(wn + r16) * BSP + kk * 32 + q4 * 8]);
#pragma unroll
      for (int i = 0; i < 4; ++i)
        acc[i] = __builtin_amdgcn_mfma_f32_16x16x32_bf16(af[i], bg, acc[i], 0, 0, 0);
    }
    __syncthreads();                    // Bs reads done before next gather
  }

  // ---- epilogue: out[(b*CC+co)*NPIX + pix] = relu(acc + bias) ----
#pragma unroll
  for (int i = 0; i < 4; ++i) {
    int pix = pix0 + wn + r16;
#pragma unroll
    for (int r = 0; r < 4; ++r) {
      int co = wm + i * 16 + q4 * 4 + r;
      float v = acc[i][r] + bias[co];
      out[(size_t)(b * CC + co) * NPIX + pix] = fmaxf(v, 0.f);
    }
  }
}

extern "C" void kernel_launch(void* const* d_in, const int* in_sizes, int n_in,
                              void* d_out, int out_size, void* d_ws, size_t ws_size,
                              hipStream_t stream) {
  const float* feat  = (const float*)d_in[0];
  const float* calib = (const float*)d_in[1];
  const float* grid  = (const float*)d_in[2];
  const float* Wc    = (const float*)d_in[3];
  const float* bc    = (const float*)d_in[4];
  float* out = (float*)d_out;

  char* ws = (char*)d_ws;
  const size_t SZ_INTEG = (size_t)BB * HH * WW * CC * 4;   // 62,914,560
  const size_t SZ_VOX   = (size_t)NDIM * KDIM * 2;         // 83,886,080 (unused slot kept)
  const size_t SZ_WBF   = (size_t)CC * KDIM * 2;           //    655,360
  const size_t SZ_CRD   = (size_t)BB * NLAY * NPIX * 16;   //  2,621,440
  const size_t SZ_SCL   = (size_t)BB * NLAY * NPIX * 4;    //    655,360
  const size_t SZ_MSK   = (size_t)NGRP * NLAY;             //      1,280
  if (ws_size < SZ_INTEG + SZ_VOX + SZ_WBF + SZ_CRD + SZ_SCL + SZ_MSK) return;

  float*   integ  = (float*)ws;
  __bf16*  Wbf    = (__bf16*)(ws + SZ_INTEG + SZ_VOX);
  float4*  coords = (float4*)(ws + SZ_INTEG + SZ_VOX + SZ_WBF);
  float*   scales = (float*)(ws + SZ_INTEG + SZ_VOX + SZ_WBF + SZ_CRD);
  uint8_t* mask8  = (uint8_t*)(ws + SZ_INTEG + SZ_VOX + SZ_WBF + SZ_CRD + SZ_SCL);

  k1f<<<dim3(BB * HH * 8 + 480), dim3(1024), 0, stream>>>(
      feat, integ, grid, calib, Wc, coords, scales, Wbf, mask8);
  k2_scan<<<dim3(BB * WW), dim3(256), 0, stream>>>(integ);
  k46<<<dim3(NDIM / 32), dim3(512), 0, stream>>>(Wbf, integ, coords, scales, bc, out, mask8);
}

// Round 9
// 161.234 us; speedup vs baseline: 1.1117x; 1.1117x over previous
//
#include <hip/hip_runtime.h>
#include <hip/hip_bf16.h>
#include <stdint.h>

#define BB 2
#define CC 256
#define HH 96
#define WW 320
#define NPIX 16384
#define NLAY 5
#define KDIM 1280   // CC*NLAY
#define NDIM 32768  // BB*NPIX
#define NKT (KDIM / 32)   // 40 K-tiles
#define NGRP 256    // NDIM/128 output row groups (k6 N-tiles)

typedef float f32x4 __attribute__((ext_vector_type(4)));
typedef float f32x2 __attribute__((ext_vector_type(2)));
typedef __bf16 bf16x8 __attribute__((ext_vector_type(8)));
typedef __bf16 bf16x4 __attribute__((ext_vector_type(4)));

// ---------- K1 (+K3+K5 fused as extra blocks): ----------
// R9 = R5 (best measured, 160.3us) with k1f's K1-part swapped to the
// 1-barrier direct-read form (R3/R8): direct global run-reads, scan,
// transpose tile, float4 full-line stores. R8 bundled this with a k46
// regression; here it gets a clean A/B vs R5's 3-barrier version.
// blocks [0,480): box geometry + Wc repack + visibility mask (R5).
// blocks [480, 480+1536): cumsum along W + transpose -> (B,H,W,C).
__global__ __launch_bounds__(1024) void k1f(const float* __restrict__ feat,
                                            float* __restrict__ integ,
                                            const float* __restrict__ gridp,
                                            const float* __restrict__ calib,
                                            const float* __restrict__ Wc,
                                            float4* __restrict__ coords,
                                            float* __restrict__ scales,
                                            __bf16* __restrict__ Wbf,
                                            uint8_t* __restrict__ mask8) {
  const int bid = blockIdx.x;
  if (bid < 480) {
    // ---- K3/K5 part ----
    const int vbid = bid * 4 + (threadIdx.x >> 8);
    const int vt = threadIdx.x & 255;
    if (vbid >= 640) {                  // K5: repack Wc (co, c*5+n) -> bf16 (co, n*256+c)
      int o = (vbid - 640) * 256 + vt;
      int co = o / KDIM;
      int kk = o % KDIM;
      int n = kk >> 8;
      int c = kk & 255;
      Wbf[o] = (__bf16)Wc[co * KDIM + c * NLAY + n];
      return;
    }
    // K3: one thread per box.
    int box = vbid * 256 + vt;          // ((b*5+n)<<14) | pix
    int pix = box & (NPIX - 1);
    int bn = box >> 14;
    int n = bn % NLAY;
    int b = bn / NLAY;
    const float* cb = calib + b * 12;
    float c00 = cb[0], c01 = cb[1], c02 = cb[2], c03 = cb[3];
    float c10 = cb[4], c11 = cb[5], c12 = cb[6], c13 = cb[7];
    float c20 = cb[8], c21 = cb[9], c22 = cb[10], c23 = cb[11];
    float gx = gridp[pix * 3 + 0], gy = gridp[pix * 3 + 1], gz = gridp[pix * 3 + 2];
    float zoff = 32.0f * (float)n;
    const float ox[8] = {-12.5f, 12.5f, 12.5f, -12.5f, -12.5f, 12.5f, 12.5f, -12.5f};
    const float oy[8] = {-12.5f, -12.5f, 12.5f, 12.5f, -12.5f, -12.5f, 12.5f, 12.5f};
    float xmn = 1e30f, ymn = 1e30f, xmx = -1e30f, ymx = -1e30f;
#pragma unroll
    for (int k = 0; k < 8; ++k) {
      float X = gx + ox[k];
      float Y = gy + oy[k];
      float Z = gz + zoff + ((k >= 4) ? 32.0f : 0.0f);
      float px = c00 * X + c01 * Y + c02 * Z + c03;
      float py = c10 * X + c11 * Y + c12 * Z + c13;
      float pz = c20 * X + c21 * Y + c22 * Z + c23;
      float d = fmaxf(pz, 1e-6f);
      float nx = fminf(fmaxf(2.0f * (px / d) / 320.0f - 1.0f, -1.0f), 0.95f);
      float ny = fminf(fmaxf(2.0f * (py / d) / 96.0f - 1.0f, -1.0f), 0.95f);
      xmn = fminf(xmn, nx); xmx = fmaxf(xmx, nx);
      ymn = fminf(ymn, ny); ymx = fmaxf(ymx, ny);
    }
    float dx = xmx - xmn, dy = ymx - ymn;
    float area = (dx * dy) * 30720.0f + 1e-6f;
    bool vis = (area > 1e-6f) && (area < 9216.0f);
    {
      __shared__ uint32_t kf[16];
      unsigned long long bal = __ballot(vis);
      if ((threadIdx.x & 63) == 0) kf[threadIdx.x >> 6] = (bal != 0ull) ? 1u : 0u;
      __syncthreads();
      if (vt == 0) {
        int vb = threadIdx.x >> 8;      // vbid-local 0..3
        int vbid2 = bid * 4 + vb;
        int bn2 = vbid2 >> 6;
        int n2 = bn2 % NLAY, b2 = bn2 / NLAY;
        int g0 = b2 * 128 + (vbid2 & 63) * 2;
        mask8[g0 * 5 + n2]       = (uint8_t)(kf[vb * 4 + 0] | kf[vb * 4 + 1]);
        mask8[(g0 + 1) * 5 + n2] = (uint8_t)(kf[vb * 4 + 2] | kf[vb * 4 + 3]);
      }
    }
    float X0 = ((xmn + 1.0f) * 320.0f - 1.0f) * 0.5f;
    float Y0 = ((ymn + 1.0f) * 96.0f - 1.0f) * 0.5f;
    float X1 = ((xmx + 1.0f) * 320.0f - 1.0f) * 0.5f;
    float Y1 = ((ymx + 1.0f) * 96.0f - 1.0f) * 0.5f;
    coords[box] = make_float4(X0, Y0, X1, Y1);
    scales[box] = vis ? 1.0f / area : 0.0f;
    return;
  }
  // ---- K1 part: 32 channels per block, wave scans 2 channel rows ----
  __shared__ float tile[WW * 33];       // pitch 33: run-write stride 165%32=5
                                        // (2-way, free); f4-read (w+4cq) 2-way
  const int t = threadIdx.x;
  const int wave = t >> 6;
  const int lane = t & 63;
  const int kb = bid - 480;
  const int cg = kb & 7;
  const int h = (kb >> 3) % HH;
  const int b = kb / (8 * HH);
  const int c0 = cg * 32 + wave * 2;
  const float* s0 = feat + (size_t)((b * CC + c0) * HH + h) * WW;
  const float* s1 = s0 + (size_t)HH * WW;

  float va[5], vb[5];
#pragma unroll
  for (int j = 0; j < 5; ++j) va[j] = s0[lane * 5 + j];
#pragma unroll
  for (int j = 0; j < 5; ++j) vb[j] = s1[lane * 5 + j];
#pragma unroll
  for (int j = 1; j < 5; ++j) { va[j] += va[j - 1]; vb[j] += vb[j - 1]; }
  float ta = va[4], tb = vb[4];
  float ia = ta, ib = tb;
#pragma unroll
  for (int d = 1; d < 64; d <<= 1) {
    float ua = __shfl_up(ia, d, 64);
    float ub = __shfl_up(ib, d, 64);
    if (lane >= d) { ia += ua; ib += ub; }
  }
  float pa = ia - ta, pb = ib - tb;     // exclusive prefixes
#pragma unroll
  for (int j = 0; j < 5; ++j) { va[j] += pa; vb[j] += pb; }
  const int ca = wave * 2, cbn = wave * 2 + 1;
#pragma unroll
  for (int j = 0; j < 5; ++j) {
    int w = lane * 5 + j;
    tile[w * 33 + ca]  = va[j];
    tile[w * 33 + cbn] = vb[j];
  }
  __syncthreads();
  // store: float4 per thread; per wave-instr 8 w-rows x 128B full-line segs
  float* dst = integ + (size_t)((b * HH + h) * WW) * CC + cg * 32;
#pragma unroll
  for (int r = 0; r < 3; ++r) {
    int idx = r * 1024 + t;             // 0..2559
    if (idx < 2560) {
      int w = idx >> 3;
      int cq = (idx & 7) * 4;
      float4 o = make_float4(tile[w * 33 + cq + 0], tile[w * 33 + cq + 1],
                             tile[w * 33 + cq + 2], tile[w * 33 + cq + 3]);
      *(float4*)(dst + (size_t)w * CC + cq) = o;
    }
  }
}

// ---------- K2: cumsum along H, in place on (B,H,W,C) ----------
// Two-level scan, f32x4 per lane (1KB segments/wave-instr, 24-deep ILP).
__global__ __launch_bounds__(256) void k2_scan(float* __restrict__ integ) {
  const int blk = blockIdx.x;            // (b, w)
  const int w = blk % WW;
  const int b = blk / WW;
  const int g = threadIdx.x >> 6;        // 0..3 h-group
  const int l = threadIdx.x & 63;
  float* base = integ + ((size_t)(b * HH + g * 24) * WW + w) * CC + l * 4;
  const size_t stride = (size_t)WW * CC;
  f32x4 v[24];
#pragma unroll
  for (int i = 0; i < 24; ++i) v[i] = *(const f32x4*)(base + (size_t)i * stride);
#pragma unroll
  for (int i = 1; i < 24; ++i) v[i] += v[i - 1];
  __shared__ f32x4 part[4][64];
  part[g][l] = v[23];
  __syncthreads();
  f32x4 off = {0.f, 0.f, 0.f, 0.f};
#pragma unroll
  for (int gg = 0; gg < 3; ++gg)
    if (gg < g) off += part[gg][l];
#pragma unroll
  for (int i = 0; i < 24; ++i) *(f32x4*)(base + (size_t)i * stride) = v[i] + off;
}

// ---------- K4: box-filtered features -> vox (bf16), K permuted to n*256+c ----------
// FOUR boxes per wave, 4-deep memory ILP. Wave early-outs on the (128-pix
// group, layer) mask byte — skips tap loads AND zero-writes (k6 never reads
// those rows: same mask gates its K-tiles). [R5 exact]
__global__ __launch_bounds__(256) void k4_vox(const float* __restrict__ integ,
                                              const float4* __restrict__ coords,
                                              const float* __restrict__ scales,
                                              __bf16* __restrict__ voxA,
                                              const uint8_t* __restrict__ mask8) {
  const int wave = threadIdx.x >> 6;
  const int lane = threadIdx.x & 63;
  const int box0 = (blockIdx.x * 4 + wave) * 4;
  {
    const int pix0 = box0 & (NPIX - 1);
    const int bn0 = box0 >> 14;
    const int n0 = bn0 % NLAY, b0 = bn0 / NLAY;
    if (mask8[((b0 * NPIX + pix0) >> 7) * 5 + n0] == 0) return;  // wave-uniform
  }
#pragma unroll
  for (int u = 0; u < 4; ++u) {
    const int box = box0 + u;
    const int pix = box & (NPIX - 1);
    const int bn = box >> 14;
    const int n = bn % NLAY;
    const int b = bn / NLAY;
    const size_t row = (size_t)(b * NPIX + pix);
    bf16x4* dst = (bf16x4*)(voxA + row * KDIM + n * CC + lane * 4);
    const float scale = scales[box];
    if (scale == 0.f) {                 // wave-uniform branch
      *dst = bf16x4{(__bf16)0.f, (__bf16)0.f, (__bf16)0.f, (__bf16)0.f};
      continue;
    }
    const float4 q = coords[box];

    float xw[4]; int xi[4];
    float yw[4]; int yi[4];
    {
      float f0 = floorf(q.x); int i0 = (int)f0; float w1 = q.x - f0;
      xw[0] = (i0 >= 0 && i0 < WW) ? (1.f - w1) : 0.f;
      xw[1] = (i0 + 1 < WW) ? w1 : 0.f;
      xi[0] = min(max(i0, 0), WW - 1); xi[1] = min(max(i0 + 1, 0), WW - 1);
      float f1 = floorf(q.z); int i1 = (int)f1; float v1 = q.z - f1;
      xw[2] = (i1 >= 0 && i1 < WW) ? -(1.f - v1) : 0.f;
      xw[3] = (i1 + 1 < WW) ? -v1 : 0.f;
      xi[2] = min(max(i1, 0), WW - 1); xi[3] = min(max(i1 + 1, 0), WW - 1);
    }
    {
      float f0 = floorf(q.y); int j0 = (int)f0; float w1 = q.y - f0;
      yw[0] = (j0 >= 0 && j0 < HH) ? (1.f - w1) : 0.f;
      yw[1] = (j0 + 1 < HH) ? w1 : 0.f;
      yi[0] = min(max(j0, 0), HH - 1); yi[1] = min(max(j0 + 1, 0), HH - 1);
      float f1 = floorf(q.w); int j1 = (int)f1; float v1 = q.w - f1;
      yw[2] = (j1 >= 0 && j1 < HH) ? -(1.f - v1) : 0.f;
      yw[3] = (j1 + 1 < HH) ? -v1 : 0.f;
      yi[2] = min(max(j1, 0), HH - 1); yi[3] = min(max(j1 + 1, 0), HH - 1);
    }
    const float* base = integ + (size_t)(b * HH) * WW * CC + lane * 4;
    f32x4 val = {0.f, 0.f, 0.f, 0.f};
#pragma unroll
    for (int jj = 0; jj < 4; ++jj) {
      if (yw[jj] == 0.f) continue;          // wave-uniform branch
      const float* rp = base + (size_t)yi[jj] * WW * CC;
      f32x4 rs = {0.f, 0.f, 0.f, 0.f};
#pragma unroll
      for (int ii = 0; ii < 4; ++ii) {
        if (xw[ii] != 0.f) {
          f32x4 v = *(const f32x4*)(rp + (size_t)xi[ii] * CC);
          rs += xw[ii] * v;
        }
      }
      val += yw[jj] * rs;
    }
    val *= scale;
    *dst = bf16x4{(__bf16)val.x, (__bf16)val.y, (__bf16)val.z, (__bf16)val.w};
  }
}

// ---------- async 16B global -> LDS ----------
__device__ __forceinline__ void glds16(const void* g, void* l) {
  __builtin_amdgcn_global_load_lds(
      (const __attribute__((address_space(1))) void*)g,
      (__attribute__((address_space(3))) void*)(uint32_t)(uintptr_t)l,
      16, 0, 0);
}

// ---------- K6: GEMM  C[co, r] = sum_k Wbf[co,k] * vox[r,k]; +bias, relu ----------
// M=256, N=32768, K=1280. 128x128 tiles, bf16 MFMA 16x16x32, 4-buffer LDS
// ring, depth-3 glds prefetch, in-flight-aware vmcnt + raw s_barrier.
// K-loop over the COMPRESSED active K-tile list (8 per visible layer). [R5]
__global__ __launch_bounds__(256) void k6_gemm(const __bf16* __restrict__ A,   // 256 x 1280
                                               const __bf16* __restrict__ Bm,  // 32768 x 1280
                                               const float* __restrict__ bias,
                                               float* __restrict__ out,
                                               const uint8_t* __restrict__ mask8) {
  __shared__ __align__(16) __bf16 As[4][128 * 32];
  __shared__ __align__(16) __bf16 Bs[4][128 * 32];
  __shared__ uint8_t ktsS[NKT];
  __shared__ int LsS;
  const int tileM = blockIdx.y * 128;
  const int tileN = blockIdx.x * 128;
  const int tid = threadIdx.x;
  const int lane = tid & 63;
  const int wave = tid >> 6;
  const int wm = (wave >> 1) * 64;
  const int wn = (wave & 1) * 64;

  if (tid == 0) {
    const uint8_t* mg = mask8 + blockIdx.x * 5;   // N-tile group == blockIdx.x
    int L = 0;
#pragma unroll
    for (int n = 0; n < NLAY; ++n)
      if (mg[n]) {
#pragma unroll
        for (int kk = 0; kk < 8; ++kk) ktsS[L++] = (uint8_t)(n * 8 + kk);
      }
    LsS = L;
  }

  f32x4 acc[4][4];
#pragma unroll
  for (int i = 0; i < 4; ++i)
#pragma unroll
    for (int j = 0; j < 4; ++j)
      acc[i][j] = f32x4{0.f, 0.f, 0.f, 0.f};

  const int r16 = lane & 15;
  const int q4 = lane >> 4;        // 0..3 -> k-chunk
  const int srow = (lane >> 2);
  const int sch = lane & 3;

  auto stage = [&](int buf, int kt) {
    const int k0 = kt * 32;
#pragma unroll
    for (int rr = 0; rr < 2; ++rr) {
      const int base_row = wave * 16 + rr * 64;
      const int row = base_row + srow;
      const int gch = sch ^ ((row >> 1) & 3);
      glds16(A  + (size_t)(tileM + row) * KDIM + k0 + gch * 8,
             (void*)(&As[buf][base_row * 32] + lane * 8));
      glds16(Bm + (size_t)(tileN + row) * KDIM + k0 + gch * 8,
             (void*)(&Bs[buf][base_row * 32] + lane * 8));
    }
  };

  __syncthreads();                       // ktsS/LsS visible
  const int L = LsS;
#pragma unroll
  for (int s = 0; s < 3; ++s)
    if (s < L) stage(s, ktsS[s]);
  for (int i = 0; i < L; ++i) {
    const int cur = i & 3;
    const int rem = L - i;               // stages in flight = min(rem, 3)
    if (rem >= 3)      __builtin_amdgcn_s_waitcnt(0xF78);  // vmcnt(8)
    else if (rem == 2) __builtin_amdgcn_s_waitcnt(0xF74);  // vmcnt(4)
    else               __builtin_amdgcn_s_waitcnt(0xF70);  // vmcnt(0)
    __builtin_amdgcn_s_barrier();
    if (i + 3 < L) stage((i + 3) & 3, ktsS[i + 3]);   // async prefetch, depth 3
    bf16x8 af[4], bg[4];
#pragma unroll
    for (int ii = 0; ii < 4; ++ii) {
      int m = wm + ii * 16 + r16;
      af[ii] = *(const bf16x8*)(&As[cur][m * 32] + (q4 ^ ((m >> 1) & 3)) * 8);
    }
#pragma unroll
    for (int j = 0; j < 4; ++j) {
      int nr = wn + j * 16 + r16;
      bg[j] = *(const bf16x8*)(&Bs[cur][nr * 32] + (q4 ^ ((nr >> 1) & 3)) * 8);
    }
#pragma unroll
    for (int ii = 0; ii < 4; ++ii)
#pragma unroll
      for (int j = 0; j < 4; ++j)
        acc[ii][j] = __builtin_amdgcn_mfma_f32_16x16x32_bf16(af[ii], bg[j], acc[ii][j], 0, 0, 0);
  }

#pragma unroll
  for (int i = 0; i < 4; ++i) {
#pragma unroll
    for (int j = 0; j < 4; ++j) {
      int nn = tileN + wn + j * 16 + r16;
      int bI = nn >> 14;
      int pix = nn & (NPIX - 1);
#pragma unroll
      for (int r = 0; r < 4; ++r) {
        int co = tileM + wm + i * 16 + q4 * 4 + r;
        float v = acc[i][j][r] + bias[co];
        out[(size_t)(bI * CC + co) * NPIX + pix] = fmaxf(v, 0.f);
      }
    }
  }
}

extern "C" void kernel_launch(void* const* d_in, const int* in_sizes, int n_in,
                              void* d_out, int out_size, void* d_ws, size_t ws_size,
                              hipStream_t stream) {
  const float* feat  = (const float*)d_in[0];
  const float* calib = (const float*)d_in[1];
  const float* grid  = (const float*)d_in[2];
  const float* Wc    = (const float*)d_in[3];
  const float* bc    = (const float*)d_in[4];
  float* out = (float*)d_out;

  char* ws = (char*)d_ws;
  const size_t SZ_INTEG = (size_t)BB * HH * WW * CC * 4;   // 62,914,560
  const size_t SZ_VOX   = (size_t)NDIM * KDIM * 2;         // 83,886,080
  const size_t SZ_WBF   = (size_t)CC * KDIM * 2;           //    655,360
  const size_t SZ_CRD   = (size_t)BB * NLAY * NPIX * 16;   //  2,621,440
  const size_t SZ_SCL   = (size_t)BB * NLAY * NPIX * 4;    //    655,360
  const size_t SZ_MSK   = (size_t)NGRP * NLAY;             //      1,280
  if (ws_size < SZ_INTEG + SZ_VOX + SZ_WBF + SZ_CRD + SZ_SCL + SZ_MSK) return;

  float*   integ  = (float*)ws;
  __bf16*  voxA   = (__bf16*)(ws + SZ_INTEG);
  __bf16*  Wbf    = (__bf16*)(ws + SZ_INTEG + SZ_VOX);
  float4*  coords = (float4*)(ws + SZ_INTEG + SZ_VOX + SZ_WBF);
  float*   scales = (float*)(ws + SZ_INTEG + SZ_VOX + SZ_WBF + SZ_CRD);
  uint8_t* mask8  = (uint8_t*)(ws + SZ_INTEG + SZ_VOX + SZ_WBF + SZ_CRD + SZ_SCL);

  k1f<<<dim3(BB * HH * 8 + 480), dim3(1024), 0, stream>>>(
      feat, integ, grid, calib, Wc, coords, scales, Wbf, mask8);
  k2_scan<<<dim3(BB * WW), dim3(256), 0, stream>>>(integ);
  k4_vox<<<dim3(BB * NLAY * NPIX / 16), dim3(256), 0, stream>>>(integ, coords, scales, voxA, mask8);
  k6_gemm<<<dim3(NDIM / 128, 2), dim3(256), 0, stream>>>(Wbf, voxA, bc, out, mask8);
}